// Round 2
// baseline (33637.256 us; speedup 1.0000x reference)
//
#include <hip/hip_runtime.h>

// LSTM 2-layer persistent cooperative kernel. T=512, B=64, I=H=1024.
// 256 blocks (1/CU) x 512 threads (8 waves = 4 m-tiles x 2 K-halves).
// Weights (bf16, Wcat=[Wx|Wh] per layer) live in LDS for all steps.
// Layer pipeline: slot s computes layer0(t=s) and layer1(t=s-1); one grid
// barrier per slot. c-state is one fp32 register per lane for 512 steps.

#define T_STEPS 512
#define BH      65536            // 64 * 1024
#define NBLK    256
#define NTHR    512
#define LDSTRW  2056             // W row stride in LDS (2048 + 8 pad)
#define WSLICE  (16 * LDSTRW)    // elems per layer slice
#define SMEM_BYTES (4 * WSLICE + 8192)   // 2 slices * 2B + 8KB reduction

typedef __bf16 bf16x8 __attribute__((ext_vector_type(8)));
typedef __bf16 bf16x4 __attribute__((ext_vector_type(4)));
typedef float  f32x4  __attribute__((ext_vector_type(4)));

__device__ __forceinline__ float sigm_(float x) { return 1.0f / (1.0f + __expf(-x)); }
__device__ __forceinline__ float tanh_(float x) {
    float e = __expf(-2.0f * fabsf(x));
    float t = (1.0f - e) / (1.0f + e);
    return copysignf(t, x);
}

__device__ __forceinline__ void gridbar(unsigned int* bar, unsigned int target) {
    __threadfence();                       // release: drain stores, L2 writeback (cross-XCD)
    __syncthreads();
    if (threadIdx.x == 0) {
        atomicAdd(bar, 1u);
        while (__hip_atomic_load(bar, __ATOMIC_RELAXED, __HIP_MEMORY_SCOPE_AGENT) < target) {
            __builtin_amdgcn_s_sleep(2);
        }
        __threadfence();                   // acquire: invalidate stale L1/L2 lines
    }
    __syncthreads();
}

__global__ __launch_bounds__(NTHR, 2) void lstm_persist(
    const __bf16* __restrict__ Xb,
    const __bf16* __restrict__ W0,
    const __bf16* __restrict__ W1,
    float* __restrict__ out,
    __bf16* __restrict__ h0b,
    __bf16* __restrict__ h1b,
    unsigned int* __restrict__ bar)
{
    extern __shared__ char smem[];
    __bf16* w0s = (__bf16*)smem;
    __bf16* w1s = w0s + WSLICE;
    float*  red = (float*)(smem + 4 * WSLICE);   // 8 KB: 4 waves x 2 tiles x 1KB

    const int tid = threadIdx.x;
    const int bid = blockIdx.x;
    const int w   = tid >> 6, l = tid & 63;
    const int m   = w & 3;                 // batch tile 0..3 (16 rows each)
    const int kh  = w >> 2;                // K-half 0/1
    const int n0  = bid * 4;               // this block's 4 h-columns (per layer)

    // ---- Stage weight slices into LDS. LDS row r = c*4+g  <->  Wcat row g*1024 + n0 + c.
    for (int i = tid; i < 16 * 256; i += NTHR) {
        int r  = i >> 8;
        int ko = (i & 255) * 8;
        size_t grow = (size_t)((r & 3) * 1024 + n0 + (r >> 2)) * 2048 + ko;
        *(bf16x8*)&w0s[r * LDSTRW + ko] = *(const bf16x8*)&W0[grow];
        *(bf16x8*)&w1s[r * LDSTRW + ko] = *(const bf16x8*)&W1[grow];
    }
    // ---- Zero h ping-pong buffers (ws is poisoned 0xAA each call).
    {
        int idx = bid * NTHR + tid;        // 0..131071 ; need 2*BH/8 = 16384 vec8 per buf
        if (idx < 2 * BH / 8) {
            bf16x8 z = {};
            *(bf16x8*)&h0b[idx * 8] = z;
            *(bf16x8*)&h1b[idx * 8] = z;
        }
    }
    unsigned int epoch = 0;
    gridbar(bar, ++epoch * NBLK);

    float c0r = 0.f, c1r = 0.f, lh0 = 0.f, lh1 = 0.f;
    const int arow = m * 16 + (l & 15);    // A-fragment row (batch index)
    const int lk8  = (l >> 4) * 8;         // k-offset within 32-chunk
    const int brow = (l & 15) * LDSTRW;    // B-fragment LDS row base

    for (int s = 0; s <= T_STEPS; ++s) {
        const bool en0 = (s < T_STEPS);
        const bool en1 = (s >= 1);
        const __bf16* h0p = h0b + ((s + 1) & 1) * BH;   // h0_{s-1}
        const __bf16* h1p = h1b + (s & 1) * BH;         // h1_{s-2}
        f32x4 a0 = {0.f, 0.f, 0.f, 0.f};
        f32x4 a1 = {0.f, 0.f, 0.f, 0.f};
        const int kb = kh * 512;

        if (en0) {  // x-part of layer0 (Wcat0 cols [0,1024))
            const __bf16* xa = Xb + (size_t)s * BH + arow * 1024 + kb;
            #pragma unroll
            for (int kc = 0; kc < 16; ++kc) {
                bf16x8 af = *(const bf16x8*)&xa[kc * 32 + lk8];
                bf16x8 bf = *(const bf16x8*)&w0s[brow + kb + kc * 32 + lk8];
                a0 = __builtin_amdgcn_mfma_f32_16x16x32_bf16(af, bf, a0, 0, 0, 0);
            }
        }
        {   // h0-part: feeds layer0 (Wcat0 cols 1024+k) AND layer1 x-part (Wcat1 cols k)
            const __bf16* ha = h0p + arow * 1024 + kb;
            const int o0 = brow + 1024 + kb;
            const int o1 = brow + kb;
            #pragma unroll
            for (int kc = 0; kc < 16; ++kc) {
                bf16x8 af = *(const bf16x8*)&ha[kc * 32 + lk8];
                if (en0) {
                    bf16x8 b0 = *(const bf16x8*)&w0s[o0 + kc * 32 + lk8];
                    a0 = __builtin_amdgcn_mfma_f32_16x16x32_bf16(af, b0, a0, 0, 0, 0);
                }
                if (en1) {
                    bf16x8 b1 = *(const bf16x8*)&w1s[o1 + kc * 32 + lk8];
                    a1 = __builtin_amdgcn_mfma_f32_16x16x32_bf16(af, b1, a1, 0, 0, 0);
                }
            }
        }
        if (en1) {  // h1-part of layer1 (Wcat1 cols 1024+k)
            const __bf16* ha = h1p + arow * 1024 + kb;
            const int o1 = brow + 1024 + kb;
            #pragma unroll
            for (int kc = 0; kc < 16; ++kc) {
                bf16x8 af = *(const bf16x8*)&ha[kc * 32 + lk8];
                bf16x8 b1 = *(const bf16x8*)&w1s[o1 + kc * 32 + lk8];
                a1 = __builtin_amdgcn_mfma_f32_16x16x32_bf16(af, b1, a1, 0, 0, 0);
            }
        }
        // ---- K-half reduction (waves 4..7 -> waves 0..3 via LDS).
        if (kh == 1) {
            *(f32x4*)&red[(m * 2 + 0) * 256 + l * 4] = a0;
            *(f32x4*)&red[(m * 2 + 1) * 256 + l * 4] = a1;
        }
        __syncthreads();
        if (kh == 0) {
            a0 += *(const f32x4*)&red[(m * 2 + 0) * 256 + l * 4];
            a1 += *(const f32x4*)&red[(m * 2 + 1) * 256 + l * 4];
            // D layout: col = l&15 = c*4+g, row-in-tile = (l>>4)*4 + reg.
            // Lane's cell: c = (l&15)>>2, row = m*16 + (l>>4)*4 + (l&3).
            const int q0  = (l & 48) | (l & 12);
            const int col = n0 + ((l & 15) >> 2);
            const int row = m * 16 + ((l >> 4) << 2) + (l & 3);
            if (en0) {
                #pragma unroll
                for (int r = 0; r < 4; ++r) {
                    float gi = __shfl(a0[r], q0);
                    float gj = __shfl(a0[r], q0 | 1);
                    float gf = __shfl(a0[r], q0 | 2);
                    float go = __shfl(a0[r], q0 | 3);
                    if ((l & 3) == r) {
                        float cn = c0r * sigm_(gf + 1.0f) + sigm_(gi) * tanh_(gj);
                        c0r = cn;
                        float hn = sigm_(go) * tanh_(cn);
                        lh0 = hn;
                        h0b[(s & 1) * BH + row * 1024 + col] = (__bf16)hn;
                    }
                }
            }
            if (en1) {
                #pragma unroll
                for (int r = 0; r < 4; ++r) {
                    float gi = __shfl(a1[r], q0);
                    float gj = __shfl(a1[r], q0 | 1);
                    float gf = __shfl(a1[r], q0 | 2);
                    float go = __shfl(a1[r], q0 | 3);
                    if ((l & 3) == r) {
                        float cn = c1r * sigm_(gf + 1.0f) + sigm_(gi) * tanh_(gj);
                        c1r = cn;
                        float hn = sigm_(go) * tanh_(cn);
                        lh1 = hn;
                        h1b[((s + 1) & 1) * BH + row * 1024 + col] = (__bf16)hn;
                        out[(size_t)(s - 1) * BH + row * 1024 + col] = hn;
                    }
                }
            }
        }
        gridbar(bar, ++epoch * NBLK);
    }
    // ---- Final h and c outputs (after out[T,B,H]): h0, h1, c0, c1.
    if (kh == 0) {
        const int col = n0 + ((l & 15) >> 2);
        const int row = m * 16 + ((l >> 4) << 2) + (l & 3);
        float* hout = out + (size_t)T_STEPS * BH;
        hout[row * 1024 + col]          = lh0;
        hout[BH + row * 1024 + col]     = lh1;
        hout[2 * BH + row * 1024 + col] = c0r;
        hout[3 * BH + row * 1024 + col] = c1r;
    }
}

// Wcat[n][k] = k<1024 ? Wx[n][k] : Wh[n][k-1024], fp32 -> bf16.
__global__ void convW(const float* __restrict__ Wx, const float* __restrict__ Wh,
                      __bf16* __restrict__ dst) {
    int i = blockIdx.x * 256 + threadIdx.x;
    int e = i * 4;
    int n = e >> 11;
    int k = e & 2047;
    const float* src = (k < 1024) ? (Wx + n * 1024 + k) : (Wh + n * 1024 + (k - 1024));
    float4 v = *(const float4*)src;
    bf16x4 o = { (__bf16)v.x, (__bf16)v.y, (__bf16)v.z, (__bf16)v.w };
    *(bf16x4*)(dst + e) = o;
}

__global__ void convX(const float* __restrict__ x, __bf16* __restrict__ dst) {
    int i = blockIdx.x * 256 + threadIdx.x;
    int e = i * 4;
    float4 v = *(const float4*)(x + e);
    bf16x4 o = { (__bf16)v.x, (__bf16)v.y, (__bf16)v.z, (__bf16)v.w };
    *(bf16x4*)(dst + e) = o;
}

extern "C" void kernel_launch(void* const* d_in, const int* in_sizes, int n_in,
                              void* d_out, int out_size, void* d_ws, size_t ws_size,
                              hipStream_t stream) {
    const float* x   = (const float*)d_in[0];
    const float* Wx0 = (const float*)d_in[1];
    const float* Wh0 = (const float*)d_in[2];
    const float* Wx1 = (const float*)d_in[3];
    const float* Wh1 = (const float*)d_in[4];
    float* out = (float*)d_out;

    char* p = (char*)d_ws;
    __bf16* W0c = (__bf16*)p; p += (size_t)4096 * 2048 * 2;   // 16 MB
    __bf16* W1c = (__bf16*)p; p += (size_t)4096 * 2048 * 2;   // 16 MB
    __bf16* Xb  = (__bf16*)p; p += (size_t)T_STEPS * BH * 2;  // 64 MB
    __bf16* h0b = (__bf16*)p; p += (size_t)2 * BH * 2;        // ping-pong
    __bf16* h1b = (__bf16*)p; p += (size_t)2 * BH * 2;
    unsigned int* bar = (unsigned int*)p; p += 128;

    convW<<<8192, 256, 0, stream>>>(Wx0, Wh0, W0c);
    convW<<<8192, 256, 0, stream>>>(Wx1, Wh1, W1c);
    convX<<<32768, 256, 0, stream>>>(x, Xb);
    hipMemsetAsync(bar, 0, 128, stream);

    hipFuncSetAttribute((const void*)lstm_persist,
                        hipFuncAttributeMaxDynamicSharedMemorySize, SMEM_BYTES);

    void* args[] = { (void*)&Xb, (void*)&W0c, (void*)&W1c, (void*)&out,
                     (void*)&h0b, (void*)&h1b, (void*)&bar };
    hipLaunchCooperativeKernel((void*)lstm_persist, dim3(NBLK), dim3(NTHR),
                               args, SMEM_BYTES, stream);
}